// Round 26
// baseline (31.193 us; speedup 1.0000x reference)
//
#include <hip/hip_runtime.h>
#include <hip/hip_fp16.h>

#define BATCH 8
#define NPTS  4096
#define NPER  32768           // BATCH*NPTS per cloud
#define WROWS 32              // query rows per wave (MFMA M)
#define WAVES 4
#define BLOCK (WAVES * 64)    // 256 threads
#define BROWS (WROWS * WAVES) // 128 rows per block
#define TILES (NPTS / 32)     // 128 target tiles of 32

typedef _Float16 half8  __attribute__((ext_vector_type(8)));
typedef float    f32x16 __attribute__((ext_vector_type(16)));

// Single fused kernel. grid (32, 1, 16) = 1024 blocks x 256 thr (4 waves)
// -> 4 blocks/CU = 4 waves/SIMD (R19's proven occupancy), LDS 4x33KB/CU.
// Each block scans ALL 4096 targets so its row-mins are FINAL: sqrt +
// block-sum + one atomicAdd in-kernel. Inner loop byte-identical to R19
// (2 tiles in flight, independent racc0/racc1 chains, 1-iter prefetch).
__global__ __launch_bounds__(BLOCK) void chamfer_mfma_kernel(
    const float* __restrict__ pred, const float* __restrict__ gt,
    float* __restrict__ out)
{
    const int z    = blockIdx.z;                  // pass*8 + b
    const int b    = z & 7;
    const int pass = z >> 3;
    const float* query  = (pass ? gt : pred) + (size_t)b * NPTS * 3;
    const float* target = (pass ? pred : gt) + (size_t)b * NPTS * 3;

    __shared__ uint2 sT[NPTS];                    // 32 KB packed targets
    __shared__ float swsum[WAVES];

    const int tid = threadIdx.x;

    // ---- stage + convert all targets (16 per thread) ----
#pragma unroll
    for (int i = 0; i < NPTS / BLOCK; ++i) {
        const int t = tid + i * BLOCK;
        const float* tp = target + (size_t)t * 3;
        const __half hx = __float2half(tp[0]);
        const __half hy = __float2half(tp[1]);
        const __half hz = __float2half(tp[2]);
        const float fx = __half2float(hx), fy = __half2float(hy), fz = __half2float(hz);
        const __half hg = __float2half(fmaf(fx, fx, fmaf(fy, fy, fz * fz)));
        uint2 u;
        u.x = (unsigned)__half_as_ushort(hx) | ((unsigned)__half_as_ushort(hy) << 16);
        u.y = (unsigned)__half_as_ushort(hz) | ((unsigned)__half_as_ushort(hg) << 16);
        sT[t] = u;
    }

    const int lane = tid & 63;
    const int wave = tid >> 6;
    const int l31  = lane & 31;
    const int qrow0 = blockIdx.x * BROWS + wave * WROWS;
    const unsigned bm = (lane < 32) ? 0xFFFFFFFFu : 0u;   // low-half mask

    // ---- A fragment (+ per-lane p2 for query row l31) ----
    union { half8 h; unsigned u[4]; } A;
    A.u[2] = 0; A.u[3] = 0;
    float p2;
    {
        const float* qp = query + (size_t)(qrow0 + l31) * 3;
        const __half hx = __float2half(qp[0]);
        const __half hy = __float2half(qp[1]);
        const __half hz = __float2half(qp[2]);
        const float fx = __half2float(hx), fy = __half2float(hy), fz = __half2float(hz);
        p2 = fmaf(fx, fx, fmaf(fy, fy, fz * fz));
        const __half ax = __float2half(-2.0f * fx);   // exact (f16 in, x2 exp)
        const __half ay = __float2half(-2.0f * fy);
        const __half az = __float2half(-2.0f * fz);
        A.u[0] = ((unsigned)__half_as_ushort(ax) | ((unsigned)__half_as_ushort(ay) << 16)) & bm;
        A.u[1] = ((unsigned)__half_as_ushort(az) | (0x3C00u << 16)) & bm;  // (-2z, 1.0)
    }
    __syncthreads();

    // ---- main loop: 128 tiles of 32 targets, 2 in flight, prefetch 1 ahead ----
    f32x16 racc0, racc1, cz;
#pragma unroll
    for (int i = 0; i < 16; ++i) { racc0[i] = 3.0e38f; racc1[i] = 3.0e38f; cz[i] = 0.0f; }

    uint2 c0 = sT[l31];
    uint2 c1 = sT[32 + l31];
#pragma unroll 2
    for (int mt = 0; mt < TILES; mt += 2) {
        const int nx = (mt + 2) & (TILES - 1);
        const uint2 n0 = sT[nx * 32 + l31];           // prefetch next iter
        const uint2 n1 = sT[nx * 32 + 32 + l31];

        union { half8 h; unsigned u[4]; } B0, B1;     // raw, unmasked
        B0.u[0] = c0.x; B0.u[1] = c0.y; B0.u[2] = 0; B0.u[3] = 0;
        B1.u[0] = c1.x; B1.u[1] = c1.y; B1.u[2] = 0; B1.u[3] = 0;
        const f32x16 d0 = __builtin_amdgcn_mfma_f32_32x32x16_f16(A.h, B0.h, cz, 0, 0, 0);
        const f32x16 d1 = __builtin_amdgcn_mfma_f32_32x32x16_f16(A.h, B1.h, cz, 0, 0, 0);
#pragma unroll
        for (int i = 0; i < 16; ++i) {
            racc0[i] = fminf(racc0[i], d0[i]);
            racc1[i] = fminf(racc1[i], d1[i]);
        }
        c0 = n0; c1 = n1;
    }
#pragma unroll
    for (int i = 0; i < 16; ++i) racc0[i] = fminf(racc0[i], racc1[i]);

    // ---- min over 32 columns (shfl_xor stays within each 32-lane half) ----
#pragma unroll
    for (int i = 0; i < 16; ++i) {
        float v = racc0[i];
        v = fminf(v, __shfl_xor(v, 1));
        v = fminf(v, __shfl_xor(v, 2));
        v = fminf(v, __shfl_xor(v, 4));
        v = fminf(v, __shfl_xor(v, 8));
        v = fminf(v, __shfl_xor(v, 16));
        racc0[i] = v;
    }

    // ---- finalize: d2 -> sqrt -> wave/block sum -> one atomicAdd ----
    float wsum = 0.0f;
#pragma unroll
    for (int i = 0; i < 16; ++i) {
        const int row = (i & 3) + 8 * (i >> 2) + 4 * (lane >> 5);  // < 32
        const float p2r = __shfl(p2, row);        // all lanes participate
        if (l31 == 0) wsum += sqrtf(fmaxf(racc0[i] + p2r, 0.0f));
    }
    wsum += __shfl_xor(wsum, 32);                 // combine lanes 0 and 32
    if (lane == 0) swsum[wave] = wsum;
    __syncthreads();

    if (tid == 0) {
        atomicAdd(out, (swsum[0] + swsum[1] + swsum[2] + swsum[3])
                       * (1.0f / (float)NPER));
    }
}

extern "C" void kernel_launch(void* const* d_in, const int* in_sizes, int n_in,
                              void* d_out, int out_size, void* d_ws, size_t ws_size,
                              hipStream_t stream) {
    const float* pred = (const float*)d_in[0];
    const float* gt   = (const float*)d_in[1];

    hipMemsetAsync(d_out, 0, sizeof(float), stream);

    dim3 grid(NPTS / BROWS, 1, 2 * BATCH);
    chamfer_mfma_kernel<<<grid, BLOCK, 0, stream>>>(pred, gt, (float*)d_out);
}

// Round 27
// 21.502 us; speedup vs baseline: 1.4507x; 1.4507x over previous
//
#include <hip/hip_runtime.h>
#include <hip/hip_fp16.h>

#define BATCH 8
#define NPTS  4096
#define NPER  32768           // BATCH*NPTS per cloud
#define NQTOT (2 * NPER)      // 65536 query slots (both passes)
#define WROWS 32              // query rows per wave (MFMA M)
#define WAVES 8
#define BLOCK (WAVES * 64)    // 512 threads
#define BROWS (WROWS * WAVES) // 256 rows per block
#define NSPLIT 2              // target splits (R19 optimum)
#define HALFT (NPTS / NSPLIT) // 2048 targets per block
#define TILES (HALFT / 32)    // 64 tiles of 32

typedef _Float16 half8  __attribute__((ext_vector_type(8)));
typedef float    f32x16 __attribute__((ext_vector_type(16)));

// ws layout: float partial[NSPLIT][65536] : per-target-split min d2 (512 KB)

// K1 (R25 best @21.57us + T5 setprio): grid (16, 2, 16) = 512 blocks x 512
// thr (8 waves) -> 2 blocks/CU, 4 waves/SIMD. One mfma_f32_32x32x16_f16 per
// 32x32 tile; A masked to lanes<32 so B needs no masking; TWO tiles in
// flight with independent racc0/racc1 min chains; 1-iter LDS prefetch.
// NEW: s_setprio(1) around the MFMA+min cluster — waves here are barrier-
// free and phase-staggered (attn-like, m191), so priority keeps the MFMA
// wave fed while co-resident waves stage/epilogue.
__global__ __launch_bounds__(BLOCK) void chamfer_mfma_kernel(
    const float* __restrict__ pred, const float* __restrict__ gt,
    float* __restrict__ partial, float* __restrict__ out)
{
    const int z    = blockIdx.z;                  // pass*8 + b
    const int b    = z & 7;
    const int pass = z >> 3;
    const int half = blockIdx.y;
    const float* query  = (pass ? gt : pred) + (size_t)b * NPTS * 3;
    const float* target = (pass ? pred : gt) + (size_t)b * NPTS * 3
                        + (size_t)half * HALFT * 3;

    __shared__ uint2 sT[HALFT];                   // 16 KB packed targets

    const int tid = threadIdx.x;

    if (blockIdx.x == 0 && half == 0 && z == 0 && tid == 0) out[0] = 0.0f;

    // ---- stage + convert this split's targets (4 per thread) ----
#pragma unroll
    for (int i = 0; i < HALFT / BLOCK; ++i) {
        const int t = tid + i * BLOCK;
        const float* tp = target + (size_t)t * 3;
        const __half hx = __float2half(tp[0]);
        const __half hy = __float2half(tp[1]);
        const __half hz = __float2half(tp[2]);
        const float fx = __half2float(hx), fy = __half2float(hy), fz = __half2float(hz);
        const __half hg = __float2half(fmaf(fx, fx, fmaf(fy, fy, fz * fz)));
        uint2 u;
        u.x = (unsigned)__half_as_ushort(hx) | ((unsigned)__half_as_ushort(hy) << 16);
        u.y = (unsigned)__half_as_ushort(hz) | ((unsigned)__half_as_ushort(hg) << 16);
        sT[t] = u;
    }

    const int lane = tid & 63;
    const int wave = tid >> 6;
    const int l31  = lane & 31;
    const int qrow0 = blockIdx.x * BROWS + wave * WROWS;
    const unsigned bm = (lane < 32) ? 0xFFFFFFFFu : 0u;   // low-half mask

    // ---- A fragment (+ per-lane p2 for query row l31) ----
    union { half8 h; unsigned u[4]; } A;
    A.u[2] = 0; A.u[3] = 0;
    float p2;
    {
        const float* qp = query + (size_t)(qrow0 + l31) * 3;
        const __half hx = __float2half(qp[0]);
        const __half hy = __float2half(qp[1]);
        const __half hz = __float2half(qp[2]);
        const float fx = __half2float(hx), fy = __half2float(hy), fz = __half2float(hz);
        p2 = fmaf(fx, fx, fmaf(fy, fy, fz * fz));
        const __half ax = __float2half(-2.0f * fx);   // exact (f16 in, x2 exp)
        const __half ay = __float2half(-2.0f * fy);
        const __half az = __float2half(-2.0f * fz);
        A.u[0] = ((unsigned)__half_as_ushort(ax) | ((unsigned)__half_as_ushort(ay) << 16)) & bm;
        A.u[1] = ((unsigned)__half_as_ushort(az) | (0x3C00u << 16)) & bm;  // (-2z, 1.0)
    }
    __syncthreads();

    // ---- main loop: 64 tiles of 32 targets, 2 in flight, prefetch 1 ahead ----
    f32x16 racc0, racc1, cz;
#pragma unroll
    for (int i = 0; i < 16; ++i) { racc0[i] = 3.0e38f; racc1[i] = 3.0e38f; cz[i] = 0.0f; }

    uint2 c0 = sT[l31];
    uint2 c1 = sT[32 + l31];
#pragma unroll 2
    for (int mt = 0; mt < TILES; mt += 2) {
        const int nx = (mt + 2) & (TILES - 1);
        const uint2 n0 = sT[nx * 32 + l31];           // prefetch next iter
        const uint2 n1 = sT[nx * 32 + 32 + l31];

        union { half8 h; unsigned u[4]; } B0, B1;     // raw, unmasked
        B0.u[0] = c0.x; B0.u[1] = c0.y; B0.u[2] = 0; B0.u[3] = 0;
        B1.u[0] = c1.x; B1.u[1] = c1.y; B1.u[2] = 0; B1.u[3] = 0;
        __builtin_amdgcn_s_setprio(1);
        const f32x16 d0 = __builtin_amdgcn_mfma_f32_32x32x16_f16(A.h, B0.h, cz, 0, 0, 0);
        const f32x16 d1 = __builtin_amdgcn_mfma_f32_32x32x16_f16(A.h, B1.h, cz, 0, 0, 0);
#pragma unroll
        for (int i = 0; i < 16; ++i) {
            racc0[i] = fminf(racc0[i], d0[i]);
            racc1[i] = fminf(racc1[i], d1[i]);
        }
        __builtin_amdgcn_s_setprio(0);
        c0 = n0; c1 = n1;
    }
#pragma unroll
    for (int i = 0; i < 16; ++i) racc0[i] = fminf(racc0[i], racc1[i]);

    // ---- min over 32 columns (shfl_xor stays within each 32-lane half) ----
#pragma unroll
    for (int i = 0; i < 16; ++i) {
        float v = racc0[i];
        v = fminf(v, __shfl_xor(v, 1));
        v = fminf(v, __shfl_xor(v, 2));
        v = fminf(v, __shfl_xor(v, 4));
        v = fminf(v, __shfl_xor(v, 8));
        v = fminf(v, __shfl_xor(v, 16));
        racc0[i] = v;
    }

    // ---- write partial d2 per row (lanes 0 and 32 hold 16 rows each) ----
    float* dst = partial + (size_t)half * NQTOT + (size_t)z * NPTS + qrow0;
#pragma unroll
    for (int i = 0; i < 16; ++i) {
        const int row = (i & 3) + 8 * (i >> 2) + 4 * (lane >> 5);  // < 32
        const float p2r = __shfl(p2, row);        // all lanes participate
        if (l31 == 0) {
            dst[row] = fmaxf(racc0[i] + p2r, 0.0f);
        }
    }
}

// K2: 64 blocks x 1024. Thread j: min over the 2 target splits, sqrt, then
// wave-shuffle double sum (no syncs) + 16-value LDS tree (2 syncs),
// one atomicAdd per block.
__global__ __launch_bounds__(1024) void reduce_kernel(
    const float* __restrict__ partial, float* __restrict__ out)
{
    const int tid  = threadIdx.x;
    const int lane = tid & 63;
    const int wave = tid >> 6;
    const int j    = blockIdx.x * 1024 + tid;     // 0..65535

    const float m = fminf(partial[j], partial[NQTOT + j]);
    double v = (double)sqrtf(m);
#pragma unroll
    for (int off = 32; off > 0; off >>= 1) {
        v += __shfl_down(v, off);
    }

    __shared__ double sd[16];
    if (lane == 0) sd[wave] = v;
    __syncthreads();
    if (wave == 0) {
        double s = (lane < 16) ? sd[lane] : 0.0;
#pragma unroll
        for (int off = 8; off > 0; off >>= 1) {
            s += __shfl_down(s, off);
        }
        if (lane == 0) atomicAdd(out, (float)(s / (double)NPER));
    }
}

extern "C" void kernel_launch(void* const* d_in, const int* in_sizes, int n_in,
                              void* d_out, int out_size, void* d_ws, size_t ws_size,
                              hipStream_t stream) {
    const float* pred = (const float*)d_in[0];
    const float* gt   = (const float*)d_in[1];

    float* partial = (float*)d_ws;                // 512 KB

    dim3 grid(NPTS / BROWS, NSPLIT, 2 * BATCH);
    chamfer_mfma_kernel<<<grid, BLOCK, 0, stream>>>(pred, gt, partial, (float*)d_out);

    reduce_kernel<<<NQTOT / 1024, 1024, 0, stream>>>(partial, (float*)d_out);
}